// Round 1
// baseline (549.115 us; speedup 1.0000x reference)
//
#include <hip/hip_runtime.h>
#include <cstdint>
#include <cstddef>

// SecureFeedForward: out = relu(x @ W1^T + b1) @ W2^T + b2
// x:[16384,1024] f32, W1:[4096,1024], W2:[1024,4096], out:[16384,1024] f32.
// Strategy: cast inputs to bf16, two MFMA GEMMs (m97 128^2-tile structure,
// 16x16x32 bf16 MFMA, global_load_lds width=16). GEMM1 epilogue fuses
// bias+ReLU+bf16 cast; GEMM2 epilogue fuses bias + f32 store.

typedef __bf16 bf16x8 __attribute__((ext_vector_type(8)));
typedef float f32x4 __attribute__((ext_vector_type(4)));

__device__ __forceinline__ unsigned short f32_to_bf16_rn(float f) {
  union { float f; unsigned int u; } v; v.f = f;
  unsigned int u = v.u;
  u += 0x7fffu + ((u >> 16) & 1u);   // round-to-nearest-even
  return (unsigned short)(u >> 16);
}

__global__ void cvt_f32_bf16(const float* __restrict__ in,
                             unsigned short* __restrict__ out, int n4) {
  int i = blockIdx.x * blockDim.x + threadIdx.x;
  const int stride = gridDim.x * blockDim.x;
  for (; i < n4; i += stride) {
    const float4 v = reinterpret_cast<const float4*>(in)[i];
    ushort4 o;
    o.x = f32_to_bf16_rn(v.x);
    o.y = f32_to_bf16_rn(v.y);
    o.z = f32_to_bf16_rn(v.z);
    o.w = f32_to_bf16_rn(v.w);
    reinterpret_cast<ushort4*>(out)[i] = o;
  }
}

#define BM 128
#define BN 128
#define BK 32

__device__ __forceinline__ void gload_lds16(const void* g, void* l) {
  __builtin_amdgcn_global_load_lds(
      (const __attribute__((address_space(1))) void*)g,
      (__attribute__((address_space(3))) void*)l,
      16, 0, 0);
}

// A:[M,K] bf16 row-major, B:[N,K] bf16 row-major (i.e. B^T layout), both
// K-contiguous. C = A @ B^T + bias, optionally relu + bf16 output.
template <int OUT_RELU_BF16>
__global__ __launch_bounds__(256) void gemm_bt(
    const unsigned short* __restrict__ A,
    const unsigned short* __restrict__ B,
    const float* __restrict__ bias,
    void* __restrict__ Cout,
    int M, int N, int K) {
  __shared__ unsigned short Als[BM * BK];  // 8 KiB
  __shared__ unsigned short Bls[BN * BK];  // 8 KiB

  const int tid = threadIdx.x;
  const int w = tid >> 6;        // wave 0..3 -> 2x2 wave grid
  const int l = tid & 63;
  const int bm = blockIdx.y * BM;
  const int bn = blockIdx.x * BN;
  const int wm = (w >> 1) * 64;  // wave row offset in tile
  const int wn = (w & 1) * 64;   // wave col offset in tile

  f32x4 acc[4][4];
#pragma unroll
  for (int i = 0; i < 4; i++)
#pragma unroll
    for (int j = 0; j < 4; j++) { f32x4 z = 0.f; acc[i][j] = z; }

  // --- staging geometry (global_load_lds: wave-uniform LDS base + lane*16B)
  // Each 1 KiB chunk = 16 rows of 64 B. Wave w stages chunks {2w, 2w+1} of
  // A and of B. Lane l covers row l/4, 16-byte col (l%4) within its chunk.
  const int srow = l >> 2;
  const int scolb = (l & 3) * 16;
  const size_t strideB = (size_t)K * 2;  // bytes per row

  const char* Ag = (const char*)A + (size_t)bm * strideB + scolb;
  const char* Bg = (const char*)B + (size_t)bn * strideB + scolb;
  const int r0 = w * 32 + srow;
  const int r1 = w * 32 + 16 + srow;

  unsigned short* lA0 = &Als[(w * 32) * BK];
  unsigned short* lA1 = &Als[(w * 32 + 16) * BK];
  unsigned short* lB0 = &Bls[(w * 32) * BK];
  unsigned short* lB1 = &Bls[(w * 32 + 16) * BK];

  // --- fragment read geometry (16x16x32: A row = l&15, k = (l>>4)*8 + 0..7)
  const int fr = l & 15;
  const int fk = (l >> 4) * 8;

  for (int k0 = 0; k0 < K; k0 += BK) {
    const size_t koff = (size_t)k0 * 2;
    gload_lds16(Ag + (size_t)r0 * strideB + koff, lA0);
    gload_lds16(Ag + (size_t)r1 * strideB + koff, lA1);
    gload_lds16(Bg + (size_t)r0 * strideB + koff, lB0);
    gload_lds16(Bg + (size_t)r1 * strideB + koff, lB1);
    __syncthreads();  // drains vmcnt -> staged tile visible

    bf16x8 a[4], b[4];
#pragma unroll
    for (int i = 0; i < 4; i++) {
      a[i] = *reinterpret_cast<const bf16x8*>(&Als[(wm + i * 16 + fr) * BK + fk]);
      b[i] = *reinterpret_cast<const bf16x8*>(&Bls[(wn + i * 16 + fr) * BK + fk]);
    }
#pragma unroll
    for (int i = 0; i < 4; i++)
#pragma unroll
      for (int j = 0; j < 4; j++)
        acc[i][j] = __builtin_amdgcn_mfma_f32_16x16x32_bf16(a[i], b[j], acc[i][j], 0, 0, 0);
    __syncthreads();  // compute done before next stage overwrites LDS
  }

  // --- epilogue: C row = (l>>4)*4 + r, col = l&15 within each 16x16 frag
  const int crow0 = bm + wm + (l >> 4) * 4;
  const int ccol0 = bn + wn + fr;
  if (OUT_RELU_BF16) {
    unsigned short* C = (unsigned short*)Cout;
#pragma unroll
    for (int j = 0; j < 4; j++) {
      const int col = ccol0 + j * 16;
      const float bv = bias[col];
#pragma unroll
      for (int i = 0; i < 4; i++) {
#pragma unroll
        for (int r = 0; r < 4; r++) {
          const int row = crow0 + i * 16 + r;
          float v = acc[i][j][r] + bv;
          v = fmaxf(v, 0.0f);
          C[(size_t)row * N + col] = f32_to_bf16_rn(v);
        }
      }
    }
  } else {
    float* C = (float*)Cout;
#pragma unroll
    for (int j = 0; j < 4; j++) {
      const int col = ccol0 + j * 16;
      const float bv = bias[col];
#pragma unroll
      for (int i = 0; i < 4; i++) {
#pragma unroll
        for (int r = 0; r < 4; r++) {
          const int row = crow0 + i * 16 + r;
          C[(size_t)row * N + col] = acc[i][j][r] + bv;
        }
      }
    }
  }
}

extern "C" void kernel_launch(void* const* d_in, const int* in_sizes, int n_in,
                              void* d_out, int out_size, void* d_ws, size_t ws_size,
                              hipStream_t stream) {
  const float* x  = (const float*)d_in[0];  // [16384,1024]
  const float* W1 = (const float*)d_in[1];  // [4096,1024]
  const float* b1 = (const float*)d_in[2];  // [4096]
  const float* W2 = (const float*)d_in[3];  // [1024,4096]
  const float* b2 = (const float*)d_in[4];  // [1024]
  float* out = (float*)d_out;               // [16384,1024]

  const int M = 16384, H = 1024, F = 4096;

  unsigned short* xb  = (unsigned short*)d_ws;          // M*H bf16 (32 MiB)
  unsigned short* w1b = xb + (size_t)M * H;             // F*H bf16 (8 MiB)
  unsigned short* w2b = w1b + (size_t)F * H;            // H*F bf16 (8 MiB)
  unsigned short* act = w2b + (size_t)H * F;            // M*F bf16 (128 MiB)

  cvt_f32_bf16<<<2048, 256, 0, stream>>>(x, xb, (M * H) / 4);
  cvt_f32_bf16<<<1024, 256, 0, stream>>>(W1, w1b, (F * H) / 4);
  cvt_f32_bf16<<<1024, 256, 0, stream>>>(W2, w2b, (H * F) / 4);

  // GEMM1: act = relu(x @ W1^T + b1), bf16 out. M=16384, N=4096, K=1024.
  gemm_bt<1><<<dim3(F / BN, M / BM), 256, 0, stream>>>(xb, w1b, b1, act, M, F, H);
  // GEMM2: out = act @ W2^T + b2, f32 out. M=16384, N=1024, K=4096.
  gemm_bt<0><<<dim3(H / BN, M / BM), 256, 0, stream>>>(act, w2b, b2, out, M, H, F);
}

// Round 2
// 430.669 us; speedup vs baseline: 1.2750x; 1.2750x over previous
//
#include <hip/hip_runtime.h>
#include <cstdint>
#include <cstddef>

// SecureFeedForward: out = relu(x @ W1^T + b1) @ W2^T + b2
// x:[16384,1024] f32, W1:[4096,1024], W2:[1024,4096], out:[16384,1024] f32.
// bf16 cast + two MFMA GEMMs using the 256^2 8-phase schedule (T1+T2+T3+T4+T5):
//   - BM=BN=256, BK=64 stored as two K=32 "planes" per tile (linear for
//     global_load_lds), double-buffered: LDS = 128 KiB.
//   - 8 waves (2M x 4N), per-wave output 128x64, 16 MFMA per phase.
//   - counted s_waitcnt vmcnt(6) at phases 2/4/6/8 (3 half-planes in flight,
//     never drained to 0); raw s_barrier; lgkmcnt(0)+sched_barrier per rule #18.
//   - LDS XOR swizzle phys = off ^ ((row&3)<<4) on 64B rows, applied on the
//     pre-swizzled global source AND the ds_read address (rule #21).
//   - XCD-aware block swizzle (grids 1024 / 256, both % 8 == 0).

typedef __bf16 bf16x8 __attribute__((ext_vector_type(8)));
typedef float f32x4 __attribute__((ext_vector_type(4)));

__device__ __forceinline__ unsigned short f32_to_bf16_rn(float f) {
  union { float f; unsigned int u; } v; v.f = f;
  unsigned int u = v.u;
  u += 0x7fffu + ((u >> 16) & 1u);   // round-to-nearest-even
  return (unsigned short)(u >> 16);
}

__global__ void cvt_f32_bf16(const float* __restrict__ in,
                             unsigned short* __restrict__ out, int n4) {
  int i = blockIdx.x * blockDim.x + threadIdx.x;
  const int stride = gridDim.x * blockDim.x;
  for (; i < n4; i += stride) {
    const float4 v = reinterpret_cast<const float4*>(in)[i];
    ushort4 o;
    o.x = f32_to_bf16_rn(v.x);
    o.y = f32_to_bf16_rn(v.y);
    o.z = f32_to_bf16_rn(v.z);
    o.w = f32_to_bf16_rn(v.w);
    reinterpret_cast<ushort4*>(out)[i] = o;
  }
}

__device__ __forceinline__ void gload_lds16(const void* g, void* l) {
  __builtin_amdgcn_global_load_lds(
      (const __attribute__((address_space(1))) void*)g,
      (__attribute__((address_space(3))) void*)l,
      16, 0, 0);
}

#define VMCNT6 asm volatile("s_waitcnt vmcnt(6)" ::: "memory")
#define LGKMCNT0 asm volatile("s_waitcnt lgkmcnt(0)" ::: "memory")

// LDS plane offsets: A(buf,kh) and B(buf,kh), each plane 16 KiB = [256 rows][64B]
#define APL(BUF, KH) (((BUF)*2 + (KH)) * 16384)
#define BPL(BUF, KH) (65536 + ((BUF)*2 + (KH)) * 16384)

// Stage one half-plane (256 rows x 32 bf16) of a K-tile into LDS.
// Linear LDS dest (wave-uniform base + lane*16 by HW); global source is
// pre-swizzled so that the ds_read-side XOR swizzle reads the right data.
#define STAGE(PLANEOFF, GROW, KB) do {                                          \
    gload_lds16((GROW) + (size_t)srow0 * pitch + (KB) + scol0,                  \
                lds + (PLANEOFF) + ldsw0);                                      \
    gload_lds16((GROW) + (size_t)srow1 * pitch + (KB) + scol1,                  \
                lds + (PLANEOFF) + ldsw1);                                      \
  } while (0)

#define PHASE(BUF, QK, QN, LOADA, STAGE_STMT, DOVM) do {                        \
    const unsigned char* pA_ = lds + APL(BUF, QK) + wroff + alane;              \
    const unsigned char* pB_ = lds + BPL(BUF, QK) + wcoff + alane;              \
    if (LOADA) {                                                                \
      _Pragma("unroll") for (int m_ = 0; m_ < 8; ++m_)                          \
        af[m_] = *(const bf16x8*)(pA_ + (m_ << 10));                            \
    }                                                                           \
    bfr[0] = *(const bf16x8*)(pB_ + (((QN)*2 + 0) << 10));                      \
    bfr[1] = *(const bf16x8*)(pB_ + (((QN)*2 + 1) << 10));                      \
    STAGE_STMT;                                                                 \
    __builtin_amdgcn_s_barrier();                                               \
    LGKMCNT0;                                                                   \
    __builtin_amdgcn_sched_barrier(0);                                          \
    __builtin_amdgcn_s_setprio(1);                                              \
    _Pragma("unroll") for (int m_ = 0; m_ < 8; ++m_) {                          \
      acc[m_][(QN)*2 + 0] = __builtin_amdgcn_mfma_f32_16x16x32_bf16(            \
          af[m_], bfr[0], acc[m_][(QN)*2 + 0], 0, 0, 0);                        \
      acc[m_][(QN)*2 + 1] = __builtin_amdgcn_mfma_f32_16x16x32_bf16(            \
          af[m_], bfr[1], acc[m_][(QN)*2 + 1], 0, 0, 0);                        \
    }                                                                           \
    __builtin_amdgcn_s_setprio(0);                                              \
    if (DOVM) { VMCNT6; }                                                       \
    __builtin_amdgcn_s_barrier();                                               \
    __builtin_amdgcn_sched_barrier(0);                                          \
  } while (0)

// A:[M,K] bf16 row-major, B:[N,K] bf16 row-major (B^T layout), K-contiguous.
// C = A @ B^T + bias; RELU_BF16_OUT: relu + bf16 store, else f32 store.
template <int RELU_BF16_OUT, int NBN>
__global__ __launch_bounds__(512, 2) void gemm8(
    const unsigned short* __restrict__ A,
    const unsigned short* __restrict__ B,
    const float* __restrict__ bias,
    void* __restrict__ Cout,
    int K) {
  constexpr int N = NBN * 256;
  __shared__ unsigned char lds[131072];

  const int tid = threadIdx.x;
  const int l = tid & 63;
  const int w = tid >> 6;        // wave 0..7
  const int wr = w >> 2;         // 0..1 (M)
  const int wc = w & 3;          // 0..3 (N)

  // XCD-aware bijective swizzle (gridDim.x % 8 == 0 guaranteed by launch)
  const int nwg = gridDim.x;
  const int cpx = nwg >> 3;
  const int bid = blockIdx.x;
  const int swz = (bid & 7) * cpx + (bid >> 3);
  const int bmi = swz / NBN;
  const int bni = swz % NBN;

  const size_t pitch = (size_t)K * 2;  // bytes per row (A and B share K)
  const char* Ag = (const char*)A + (size_t)(bmi << 8) * pitch;
  const char* Bg = (const char*)B + (size_t)(bni << 8) * pitch;

  // --- staging per-thread constants (two 16B chunks per half-plane) ---
  const int sd0 = tid << 4;                 // linear dest byte, round 0
  const int sd1 = sd0 + 8192;               // round 1
  const int srow0 = sd0 >> 6;
  const int srow1 = sd1 >> 6;
  const int scol0 = (sd0 & 63) ^ ((srow0 & 3) << 4);  // pre-swizzled source col
  const int scol1 = (sd1 & 63) ^ ((srow1 & 3) << 4);
  const int ldsw0 = (w << 10);              // wave-uniform LDS base, round 0
  const int ldsw1 = 8192 + (w << 10);       // round 1

  // --- fragment read per-lane constants (swizzled ds_read address) ---
  // logical: row = base + (l&15), colb = (l>>4)*16; phys colb ^= ((row&3)<<4)
  const int alane = ((l & 15) << 6) + ((((l >> 4) << 4)) ^ ((l & 3) << 4));
  const int wroff = wr << 13;   // wr * 128 rows * 64B
  const int wcoff = wc << 12;   // wc * 64 rows * 64B

  f32x4 acc[8][4];
#pragma unroll
  for (int m = 0; m < 8; ++m)
#pragma unroll
    for (int n = 0; n < 4; ++n) { f32x4 z = 0.f; acc[m][n] = z; }
  bf16x8 af[8];
  bf16x8 bfr[2];

  const int nt = K >> 6;  // K-tiles of 64 (>= 2, even)

  // --- prologue: stage t0 fully + 3 half-planes of t1 (kb(t,kh)=t*128+kh*64)
  STAGE(APL(0, 0), Ag, 0);
  STAGE(BPL(0, 0), Bg, 0);
  STAGE(APL(0, 1), Ag, 64);
  STAGE(BPL(0, 1), Bg, 64);
  STAGE(APL(1, 0), Ag, 128);
  STAGE(BPL(1, 0), Bg, 128);
  STAGE(APL(1, 1), Ag, 192);
  VMCNT6;                        // t0 fully landed; t1's 3 halves in flight
  __builtin_amdgcn_s_barrier();

  // --- main loop: 2 K-tiles / iteration, 8 phases ---
  for (int it = 0; it < (nt >> 1); ++it) {
    const int t1 = 2 * it + 1;
    int t2 = 2 * it + 2; if (t2 >= nt) t2 = 0;  // wrapped prefetch: data is
    int t3 = 2 * it + 3; if (t3 >= nt) t3 = 0;  // staged but never read
    const int kb1 = t1 << 7;
    const int kb2 = t2 << 7;
    const int kb3 = t3 << 7;

    PHASE(0, 0, 0, 1, STAGE(BPL(1, 1), Bg, kb1 + 64), 0);  // P1
    PHASE(0, 0, 1, 0, STAGE(APL(0, 0), Ag, kb2), 1);       // P2
    PHASE(0, 1, 0, 1, STAGE(BPL(0, 0), Bg, kb2), 0);       // P3
    PHASE(0, 1, 1, 0, STAGE(APL(0, 1), Ag, kb2 + 64), 1);  // P4
    PHASE(1, 0, 0, 1, STAGE(BPL(0, 1), Bg, kb2 + 64), 0);  // P5
    PHASE(1, 0, 1, 0, STAGE(APL(1, 0), Ag, kb3), 1);       // P6
    PHASE(1, 1, 0, 1, STAGE(BPL(1, 0), Bg, kb3), 0);       // P7
    PHASE(1, 1, 1, 0, STAGE(APL(1, 1), Ag, kb3 + 64), 1);  // P8
  }

  // --- epilogue: C row = (l>>4)*4 + r (A side), col = l&15 (B side) ---
  const int crow0 = (bmi << 8) + (wr << 7) + ((l >> 4) << 2);
  const int ccol0 = (bni << 8) + (wc << 6) + (l & 15);
  if (RELU_BF16_OUT) {
    unsigned short* C = (unsigned short*)Cout;
#pragma unroll
    for (int n = 0; n < 4; ++n) {
      const int col = ccol0 + (n << 4);
      const float bv = bias[col];
#pragma unroll
      for (int m = 0; m < 8; ++m) {
#pragma unroll
        for (int r = 0; r < 4; ++r) {
          float v = acc[m][n][r] + bv;
          v = fmaxf(v, 0.0f);
          C[(size_t)(crow0 + (m << 4) + r) * N + col] = f32_to_bf16_rn(v);
        }
      }
    }
  } else {
    float* C = (float*)Cout;
#pragma unroll
    for (int n = 0; n < 4; ++n) {
      const int col = ccol0 + (n << 4);
      const float bv = bias[col];
#pragma unroll
      for (int m = 0; m < 8; ++m) {
#pragma unroll
        for (int r = 0; r < 4; ++r) {
          C[(size_t)(crow0 + (m << 4) + r) * N + col] = acc[m][n][r] + bv;
        }
      }
    }
  }
}

extern "C" void kernel_launch(void* const* d_in, const int* in_sizes, int n_in,
                              void* d_out, int out_size, void* d_ws, size_t ws_size,
                              hipStream_t stream) {
  const float* x  = (const float*)d_in[0];  // [16384,1024]
  const float* W1 = (const float*)d_in[1];  // [4096,1024]
  const float* b1 = (const float*)d_in[2];  // [4096]
  const float* W2 = (const float*)d_in[3];  // [1024,4096]
  const float* b2 = (const float*)d_in[4];  // [1024]
  float* out = (float*)d_out;               // [16384,1024]

  const int M = 16384, H = 1024, F = 4096;

  unsigned short* xb  = (unsigned short*)d_ws;          // M*H bf16 (32 MiB)
  unsigned short* w1b = xb + (size_t)M * H;             // F*H bf16 (8 MiB)
  unsigned short* w2b = w1b + (size_t)F * H;            // H*F bf16 (8 MiB)
  unsigned short* act = w2b + (size_t)H * F;            // M*F bf16 (128 MiB)

  cvt_f32_bf16<<<4096, 256, 0, stream>>>(x, xb, (M * H) / 4);
  cvt_f32_bf16<<<1024, 256, 0, stream>>>(W1, w1b, (F * H) / 4);
  cvt_f32_bf16<<<1024, 256, 0, stream>>>(W2, w2b, (H * F) / 4);

  // GEMM1: act = relu(x @ W1^T + b1), bf16 out. M=16384, N=4096, K=1024.
  gemm8<1, 16><<<dim3((M / 256) * (F / 256)), 512, 0, stream>>>(xb, w1b, b1, act, H);
  // GEMM2: out = act @ W2^T + b2, f32 out. M=16384, N=1024, K=4096.
  gemm8<0, 4><<<dim3((M / 256) * (H / 256)), 512, 0, stream>>>(act, w2b, b2, out, F);
}

// Round 3
// 421.839 us; speedup vs baseline: 1.3017x; 1.0209x over previous
//
#include <hip/hip_runtime.h>
#include <cstdint>
#include <cstddef>

// SecureFeedForward: out = relu(x @ W1^T + b1) @ W2^T + b2
// x:[16384,1024] f32, W1:[4096,1024], W2:[1024,4096], out:[16384,1024] f32.
// bf16 cast + two MFMA GEMMs using the 256^2 8-phase schedule (T1+T2+T3+T4+T5).
// R2 fix: LDS XOR swizzle uses row bits 1-2 (s(row)=(row>>1)&3), because row
// bit 0 already feeds bank bit 4 via the 64B row stride. Analytically: each
// 16-lane quarter-wave -> exactly 2 lanes per 4-bank quad (2-way = free).

typedef __bf16 bf16x8 __attribute__((ext_vector_type(8)));
typedef float f32x4 __attribute__((ext_vector_type(4)));

__device__ __forceinline__ unsigned short f32_to_bf16_rn(float f) {
  union { float f; unsigned int u; } v; v.f = f;
  unsigned int u = v.u;
  u += 0x7fffu + ((u >> 16) & 1u);   // round-to-nearest-even
  return (unsigned short)(u >> 16);
}

__global__ void cvt_f32_bf16(const float* __restrict__ in,
                             unsigned short* __restrict__ out, int n4) {
  int i = blockIdx.x * blockDim.x + threadIdx.x;
  const int stride = gridDim.x * blockDim.x;
  for (; i < n4; i += stride) {
    const float4 v = reinterpret_cast<const float4*>(in)[i];
    ushort4 o;
    o.x = f32_to_bf16_rn(v.x);
    o.y = f32_to_bf16_rn(v.y);
    o.z = f32_to_bf16_rn(v.z);
    o.w = f32_to_bf16_rn(v.w);
    reinterpret_cast<ushort4*>(out)[i] = o;
  }
}

__device__ __forceinline__ void gload_lds16(const void* g, void* l) {
  __builtin_amdgcn_global_load_lds(
      (const __attribute__((address_space(1))) void*)g,
      (__attribute__((address_space(3))) void*)l,
      16, 0, 0);
}

#define VMCNT6 asm volatile("s_waitcnt vmcnt(6)" ::: "memory")
#define LGKMCNT0 asm volatile("s_waitcnt lgkmcnt(0)" ::: "memory")

// LDS plane offsets: A(buf,kh) and B(buf,kh), each plane 16 KiB = [256 rows][64B]
#define APL(BUF, KH) (((BUF)*2 + (KH)) * 16384)
#define BPL(BUF, KH) (65536 + ((BUF)*2 + (KH)) * 16384)

// Stage one half-plane (256 rows x 32 bf16) of a K-tile into LDS.
// Linear LDS dest (wave-uniform base + lane*16 by HW); global source is
// pre-swizzled so that the ds_read-side XOR swizzle reads the right data.
#define STAGE(PLANEOFF, GROW, KB) do {                                          \
    gload_lds16((GROW) + (size_t)srow0 * pitch + (KB) + scol0,                  \
                lds + (PLANEOFF) + ldsw0);                                      \
    gload_lds16((GROW) + (size_t)srow1 * pitch + (KB) + scol1,                  \
                lds + (PLANEOFF) + ldsw1);                                      \
  } while (0)

#define PHASE(BUF, QK, QN, LOADA, STAGE_STMT, DOVM) do {                        \
    const unsigned char* pA_ = lds + APL(BUF, QK) + wroff + alane;              \
    const unsigned char* pB_ = lds + BPL(BUF, QK) + wcoff + alane;              \
    if (LOADA) {                                                                \
      _Pragma("unroll") for (int m_ = 0; m_ < 8; ++m_)                          \
        af[m_] = *(const bf16x8*)(pA_ + (m_ << 10));                            \
    }                                                                           \
    bfr[0] = *(const bf16x8*)(pB_ + (((QN)*2 + 0) << 10));                      \
    bfr[1] = *(const bf16x8*)(pB_ + (((QN)*2 + 1) << 10));                      \
    STAGE_STMT;                                                                 \
    __builtin_amdgcn_s_barrier();                                               \
    LGKMCNT0;                                                                   \
    __builtin_amdgcn_sched_barrier(0);                                          \
    __builtin_amdgcn_s_setprio(1);                                              \
    _Pragma("unroll") for (int m_ = 0; m_ < 8; ++m_) {                          \
      acc[m_][(QN)*2 + 0] = __builtin_amdgcn_mfma_f32_16x16x32_bf16(            \
          af[m_], bfr[0], acc[m_][(QN)*2 + 0], 0, 0, 0);                        \
      acc[m_][(QN)*2 + 1] = __builtin_amdgcn_mfma_f32_16x16x32_bf16(            \
          af[m_], bfr[1], acc[m_][(QN)*2 + 1], 0, 0, 0);                        \
    }                                                                           \
    __builtin_amdgcn_s_setprio(0);                                              \
    if (DOVM) { VMCNT6; }                                                       \
    __builtin_amdgcn_s_barrier();                                               \
    __builtin_amdgcn_sched_barrier(0);                                          \
  } while (0)

// A:[M,K] bf16 row-major, B:[N,K] bf16 row-major (B^T layout), K-contiguous.
// C = A @ B^T + bias; RELU_BF16_OUT: relu + bf16 store, else f32 store.
template <int RELU_BF16_OUT, int NBN>
__global__ __launch_bounds__(512, 2) void gemm8(
    const unsigned short* __restrict__ A,
    const unsigned short* __restrict__ B,
    const float* __restrict__ bias,
    void* __restrict__ Cout,
    int K) {
  constexpr int N = NBN * 256;
  __shared__ unsigned char lds[131072];

  const int tid = threadIdx.x;
  const int l = tid & 63;
  const int w = tid >> 6;        // wave 0..7
  const int wr = w >> 2;         // 0..1 (M)
  const int wc = w & 3;          // 0..3 (N)

  // XCD-aware bijective swizzle (gridDim.x % 8 == 0 guaranteed by launch)
  const int nwg = gridDim.x;
  const int cpx = nwg >> 3;
  const int bid = blockIdx.x;
  const int swz = (bid & 7) * cpx + (bid >> 3);
  const int bmi = swz / NBN;
  const int bni = swz % NBN;

  const size_t pitch = (size_t)K * 2;  // bytes per row (A and B share K)
  const char* Ag = (const char*)A + (size_t)(bmi << 8) * pitch;
  const char* Bg = (const char*)B + (size_t)(bni << 8) * pitch;

  // --- staging per-thread constants (two 16B chunks per half-plane) ---
  // Swizzle (involution): phys 16B-chunk index ^= (row>>1)&3.
  const int sd0 = tid << 4;                 // linear dest byte, round 0
  const int sd1 = sd0 + 8192;               // round 1
  const int srow0 = sd0 >> 6;
  const int srow1 = sd1 >> 6;
  const int scol0 = (sd0 & 63) ^ (((sd0 >> 7) & 3) << 4);  // pre-swizzled src col
  const int scol1 = (sd1 & 63) ^ (((sd1 >> 7) & 3) << 4);
  const int ldsw0 = (w << 10);              // wave-uniform LDS base, round 0
  const int ldsw1 = 8192 + (w << 10);       // round 1

  // --- fragment read per-lane constants (swizzled ds_read address) ---
  // logical: row = base + (l&15), chunk = l>>4; phys chunk ^= (row>>1)&3.
  // (m-, wave-offsets are multiples of 16 rows -> don't touch row bits 1-2)
  const int alane = ((l & 15) << 6) + (((l >> 4) << 4) ^ (((l >> 1) & 3) << 4));
  const int wroff = wr << 13;   // wr * 128 rows * 64B
  const int wcoff = wc << 12;   // wc * 64 rows * 64B

  f32x4 acc[8][4];
#pragma unroll
  for (int m = 0; m < 8; ++m)
#pragma unroll
    for (int n = 0; n < 4; ++n) { f32x4 z = 0.f; acc[m][n] = z; }
  bf16x8 af[8];
  bf16x8 bfr[2];

  const int nt = K >> 6;  // K-tiles of 64 (>= 2, even)

  // --- prologue: stage t0 fully + 3 half-planes of t1 (kb(t,kh)=t*128+kh*64)
  STAGE(APL(0, 0), Ag, 0);
  STAGE(BPL(0, 0), Bg, 0);
  STAGE(APL(0, 1), Ag, 64);
  STAGE(BPL(0, 1), Bg, 64);
  STAGE(APL(1, 0), Ag, 128);
  STAGE(BPL(1, 0), Bg, 128);
  STAGE(APL(1, 1), Ag, 192);
  VMCNT6;                        // t0 fully landed; t1's 3 halves in flight
  __builtin_amdgcn_s_barrier();

  // --- main loop: 2 K-tiles / iteration, 8 phases ---
  for (int it = 0; it < (nt >> 1); ++it) {
    const int t1 = 2 * it + 1;
    int t2 = 2 * it + 2; if (t2 >= nt) t2 = nt - 1;  // wrapped prefetch: data
    int t3 = 2 * it + 3; if (t3 >= nt) t3 = nt - 1;  // staged but never read
    const int kb1 = t1 << 7;                         // (nt-1: L2-hot source)
    const int kb2 = t2 << 7;
    const int kb3 = t3 << 7;

    PHASE(0, 0, 0, 1, STAGE(BPL(1, 1), Bg, kb1 + 64), 0);  // P1
    PHASE(0, 0, 1, 0, STAGE(APL(0, 0), Ag, kb2), 1);       // P2
    PHASE(0, 1, 0, 1, STAGE(BPL(0, 0), Bg, kb2), 0);       // P3
    PHASE(0, 1, 1, 0, STAGE(APL(0, 1), Ag, kb2 + 64), 1);  // P4
    PHASE(1, 0, 0, 1, STAGE(BPL(0, 1), Bg, kb2 + 64), 0);  // P5
    PHASE(1, 0, 1, 0, STAGE(APL(1, 0), Ag, kb3), 1);       // P6
    PHASE(1, 1, 0, 1, STAGE(BPL(1, 0), Bg, kb3), 0);       // P7
    PHASE(1, 1, 1, 0, STAGE(APL(1, 1), Ag, kb3 + 64), 1);  // P8
  }

  // --- epilogue: C row = (l>>4)*4 + r (A side), col = l&15 (B side) ---
  const int crow0 = (bmi << 8) + (wr << 7) + ((l >> 4) << 2);
  const int ccol0 = (bni << 8) + (wc << 6) + (l & 15);
  if (RELU_BF16_OUT) {
    unsigned short* C = (unsigned short*)Cout;
#pragma unroll
    for (int n = 0; n < 4; ++n) {
      const int col = ccol0 + (n << 4);
      const float bv = bias[col];
#pragma unroll
      for (int m = 0; m < 8; ++m) {
#pragma unroll
        for (int r = 0; r < 4; ++r) {
          float v = acc[m][n][r] + bv;
          v = fmaxf(v, 0.0f);
          C[(size_t)(crow0 + (m << 4) + r) * N + col] = f32_to_bf16_rn(v);
        }
      }
    }
  } else {
    float* C = (float*)Cout;
#pragma unroll
    for (int n = 0; n < 4; ++n) {
      const int col = ccol0 + (n << 4);
      const float bv = bias[col];
#pragma unroll
      for (int m = 0; m < 8; ++m) {
#pragma unroll
        for (int r = 0; r < 4; ++r) {
          C[(size_t)(crow0 + (m << 4) + r) * N + col] = acc[m][n][r] + bv;
        }
      }
    }
  }
}

extern "C" void kernel_launch(void* const* d_in, const int* in_sizes, int n_in,
                              void* d_out, int out_size, void* d_ws, size_t ws_size,
                              hipStream_t stream) {
  const float* x  = (const float*)d_in[0];  // [16384,1024]
  const float* W1 = (const float*)d_in[1];  // [4096,1024]
  const float* b1 = (const float*)d_in[2];  // [4096]
  const float* W2 = (const float*)d_in[3];  // [1024,4096]
  const float* b2 = (const float*)d_in[4];  // [1024]
  float* out = (float*)d_out;               // [16384,1024]

  const int M = 16384, H = 1024, F = 4096;

  unsigned short* xb  = (unsigned short*)d_ws;          // M*H bf16 (32 MiB)
  unsigned short* w1b = xb + (size_t)M * H;             // F*H bf16 (8 MiB)
  unsigned short* w2b = w1b + (size_t)F * H;            // H*F bf16 (8 MiB)
  unsigned short* act = w2b + (size_t)H * F;            // M*F bf16 (128 MiB)

  cvt_f32_bf16<<<4096, 256, 0, stream>>>(x, xb, (M * H) / 4);
  cvt_f32_bf16<<<1024, 256, 0, stream>>>(W1, w1b, (F * H) / 4);
  cvt_f32_bf16<<<1024, 256, 0, stream>>>(W2, w2b, (H * F) / 4);

  // GEMM1: act = relu(x @ W1^T + b1), bf16 out. M=16384, N=4096, K=1024.
  gemm8<1, 16><<<dim3((M / 256) * (F / 256)), 512, 0, stream>>>(xb, w1b, b1, act, H);
  // GEMM2: out = act @ W2^T + b2, f32 out. M=16384, N=1024, K=4096.
  gemm8<0, 4><<<dim3((M / 256) * (H / 256)), 512, 0, stream>>>(act, w2b, b2, out, F);
}

// Round 5
// 395.548 us; speedup vs baseline: 1.3882x; 1.0665x over previous
//
#include <hip/hip_runtime.h>
#include <cstdint>
#include <cstddef>

// SecureFeedForward: out = relu(x @ W1^T + b1) @ W2^T + b2
// x:[16384,1024] f32, W1:[4096,1024], W2:[1024,4096], out:[16384,1024] f32.
// bf16 cast + two MFMA GEMMs, 256^2 8-phase schedule (T1..T5).
// R3: (a) remove forced lgkmcnt(0) full-drain before MFMA cluster — let the
//     compiler pace ds_read->MFMA with counted lgkmcnt so LDS drain overlaps
//     MFMA issue; motion pinned with sched_barrier(0) at every s_barrier.
//     (b) GEMM1 epilogue LDS-bounce -> coalesced ushort4 stores (kills the
//     2x write amplification). (c) fused cvt kernels into one launch.
// R4: resubmit (GPU acquisition timeout — no bench ran).

typedef __bf16 bf16x8 __attribute__((ext_vector_type(8)));
typedef float f32x4 __attribute__((ext_vector_type(4)));

__device__ __forceinline__ unsigned short f32_to_bf16_rn(float f) {
  union { float f; unsigned int u; } v; v.f = f;
  unsigned int u = v.u;
  u += 0x7fffu + ((u >> 16) & 1u);   // round-to-nearest-even
  return (unsigned short)(u >> 16);
}

__global__ void cvt_all(const float* __restrict__ x,
                        const float* __restrict__ w1,
                        const float* __restrict__ w2,
                        unsigned short* __restrict__ xb,
                        unsigned short* __restrict__ w1b,
                        unsigned short* __restrict__ w2b,
                        int nx4, int nw4) {
  const int stride = gridDim.x * blockDim.x;
  int i = blockIdx.x * blockDim.x + threadIdx.x;
  const int total = nx4 + 2 * nw4;
  for (; i < total; i += stride) {
    const float* src; unsigned short* dst; int j;
    if (i < nx4) { src = x; dst = xb; j = i; }
    else if (i < nx4 + nw4) { src = w1; dst = w1b; j = i - nx4; }
    else { src = w2; dst = w2b; j = i - nx4 - nw4; }
    const float4 v = reinterpret_cast<const float4*>(src)[j];
    ushort4 o;
    o.x = f32_to_bf16_rn(v.x);
    o.y = f32_to_bf16_rn(v.y);
    o.z = f32_to_bf16_rn(v.z);
    o.w = f32_to_bf16_rn(v.w);
    reinterpret_cast<ushort4*>(dst)[j] = o;
  }
}

__device__ __forceinline__ void gload_lds16(const void* g, void* l) {
  __builtin_amdgcn_global_load_lds(
      (const __attribute__((address_space(1))) void*)g,
      (__attribute__((address_space(3))) void*)l,
      16, 0, 0);
}

#define VMCNT6 asm volatile("s_waitcnt vmcnt(6)" ::: "memory")
#define VMCNT0 asm volatile("s_waitcnt vmcnt(0)" ::: "memory")
#define LGKMCNT0 asm volatile("s_waitcnt lgkmcnt(0)" ::: "memory")

// LDS plane offsets: A(buf,kh) and B(buf,kh), each plane 16 KiB = [256 rows][64B]
#define APL(BUF, KH) (((BUF)*2 + (KH)) * 16384)
#define BPL(BUF, KH) (65536 + ((BUF)*2 + (KH)) * 16384)

#define STAGE(PLANEOFF, GROW, KB) do {                                          \
    gload_lds16((GROW) + (size_t)srow0 * pitch + (KB) + scol0,                  \
                lds + (PLANEOFF) + ldsw0);                                      \
    gload_lds16((GROW) + (size_t)srow1 * pitch + (KB) + scol1,                  \
                lds + (PLANEOFF) + ldsw1);                                      \
  } while (0)

// Phase: [B-reads, (A-reads), stage] | fence+barrier+fence | MFMA (compiler-
// paced lgkm waits overlap LDS drain with MFMA issue) | [vmcnt] fence barrier.
#define PHASE(BUF, QK, QN, LOADA, STAGE_STMT, DOVM) do {                        \
    const unsigned char* pA_ = lds + APL(BUF, QK) + wroff + alane;              \
    const unsigned char* pB_ = lds + BPL(BUF, QK) + wcoff + alane;              \
    bfr[0] = *(const bf16x8*)(pB_ + (((QN)*2 + 0) << 10));                      \
    bfr[1] = *(const bf16x8*)(pB_ + (((QN)*2 + 1) << 10));                      \
    if (LOADA) {                                                                \
      _Pragma("unroll") for (int m_ = 0; m_ < 8; ++m_)                          \
        af[m_] = *(const bf16x8*)(pA_ + (m_ << 10));                            \
    }                                                                           \
    STAGE_STMT;                                                                 \
    __builtin_amdgcn_sched_barrier(0);                                          \
    __builtin_amdgcn_s_barrier();                                               \
    __builtin_amdgcn_sched_barrier(0);                                          \
    __builtin_amdgcn_s_setprio(1);                                              \
    _Pragma("unroll") for (int m_ = 0; m_ < 8; ++m_) {                          \
      acc[m_][(QN)*2 + 0] = __builtin_amdgcn_mfma_f32_16x16x32_bf16(            \
          af[m_], bfr[0], acc[m_][(QN)*2 + 0], 0, 0, 0);                        \
      acc[m_][(QN)*2 + 1] = __builtin_amdgcn_mfma_f32_16x16x32_bf16(            \
          af[m_], bfr[1], acc[m_][(QN)*2 + 1], 0, 0, 0);                        \
    }                                                                           \
    __builtin_amdgcn_s_setprio(0);                                              \
    if (DOVM) { VMCNT6; }                                                       \
    __builtin_amdgcn_sched_barrier(0);                                          \
    __builtin_amdgcn_s_barrier();                                               \
  } while (0)

// A:[M,K] bf16 row-major, B:[N,K] bf16 row-major (B^T layout), K-contiguous.
// C = A @ B^T + bias; RELU_BF16_OUT: relu + bf16 store, else f32 store.
template <int RELU_BF16_OUT, int NBN>
__global__ __launch_bounds__(512, 2) void gemm8(
    const unsigned short* __restrict__ A,
    const unsigned short* __restrict__ B,
    const float* __restrict__ bias,
    void* __restrict__ Cout,
    int K) {
  constexpr int N = NBN * 256;
  __shared__ unsigned char lds[131072];

  const int tid = threadIdx.x;
  const int l = tid & 63;
  const int w = tid >> 6;        // wave 0..7
  const int wr = w >> 2;         // 0..1 (M)
  const int wc = w & 3;          // 0..3 (N)

  // XCD-aware bijective swizzle (gridDim.x % 8 == 0 by launch config)
  const int nwg = gridDim.x;
  const int cpx = nwg >> 3;
  const int bid = blockIdx.x;
  const int swz = (bid & 7) * cpx + (bid >> 3);
  const int bmi = swz / NBN;
  const int bni = swz % NBN;

  const size_t pitch = (size_t)K * 2;  // bytes per row (A and B share K)
  const char* Ag = (const char*)A + (size_t)(bmi << 8) * pitch;
  const char* Bg = (const char*)B + (size_t)(bni << 8) * pitch;

  // --- staging constants; LDS swizzle involution: chunk ^= (row>>1)&3 ---
  const int sd0 = tid << 4;
  const int sd1 = sd0 + 8192;
  const int srow0 = sd0 >> 6;
  const int srow1 = sd1 >> 6;
  const int scol0 = (sd0 & 63) ^ (((sd0 >> 7) & 3) << 4);  // pre-swizzled src
  const int scol1 = (sd1 & 63) ^ (((sd1 >> 7) & 3) << 4);
  const int ldsw0 = (w << 10);
  const int ldsw1 = 8192 + (w << 10);

  // --- fragment read constants (swizzled ds_read address) ---
  const int alane = ((l & 15) << 6) + (((l >> 4) << 4) ^ (((l >> 1) & 3) << 4));
  const int wroff = wr << 13;   // wr * 128 rows * 64B
  const int wcoff = wc << 12;   // wc * 64 rows * 64B

  f32x4 acc[8][4];
#pragma unroll
  for (int m = 0; m < 8; ++m)
#pragma unroll
    for (int n = 0; n < 4; ++n) { f32x4 z = 0.f; acc[m][n] = z; }
  bf16x8 af[8];
  bf16x8 bfr[2];

  const int nt = K >> 6;  // K-tiles of 64 (>= 2, even)

  // --- prologue: stage t0 fully + 3 half-planes of t1 ---
  STAGE(APL(0, 0), Ag, 0);
  STAGE(BPL(0, 0), Bg, 0);
  STAGE(APL(0, 1), Ag, 64);
  STAGE(BPL(0, 1), Bg, 64);
  STAGE(APL(1, 0), Ag, 128);
  STAGE(BPL(1, 0), Bg, 128);
  STAGE(APL(1, 1), Ag, 192);
  VMCNT6;                        // t0 landed; t1's 3 halves in flight
  __builtin_amdgcn_s_barrier();

  // --- main loop: 2 K-tiles / iteration, 8 phases ---
  for (int it = 0; it < (nt >> 1); ++it) {
    const int t1 = 2 * it + 1;
    int t2 = 2 * it + 2; if (t2 >= nt) t2 = nt - 1;  // wrapped prefetch
    int t3 = 2 * it + 3; if (t3 >= nt) t3 = nt - 1;  // (L2-hot, never read)
    const int kb1 = t1 << 7;
    const int kb2 = t2 << 7;
    const int kb3 = t3 << 7;

    PHASE(0, 0, 0, 1, STAGE(BPL(1, 1), Bg, kb1 + 64), 0);  // P1
    PHASE(0, 0, 1, 0, STAGE(APL(0, 0), Ag, kb2), 1);       // P2
    PHASE(0, 1, 0, 1, STAGE(BPL(0, 0), Bg, kb2), 0);       // P3
    PHASE(0, 1, 1, 0, STAGE(APL(0, 1), Ag, kb2 + 64), 1);  // P4
    PHASE(1, 0, 0, 1, STAGE(BPL(0, 1), Bg, kb2 + 64), 0);  // P5
    PHASE(1, 0, 1, 0, STAGE(APL(1, 0), Ag, kb3), 1);       // P6
    PHASE(1, 1, 0, 1, STAGE(BPL(1, 0), Bg, kb3), 0);       // P7
    PHASE(1, 1, 1, 0, STAGE(APL(1, 1), Ag, kb3 + 64), 1);  // P8
  }

  const int crow0 = (bmi << 8) + (wr << 7) + ((l >> 4) << 2);
  const int ccol0 = (bni << 8) + (wc << 6) + (l & 15);

  if (RELU_BF16_OUT) {
    // --- LDS-bounce epilogue: coalesced ushort4 stores (no write amp) ---
    VMCNT0;                         // wrapped-prefetch stages still in flight
    __builtin_amdgcn_s_barrier();   // LDS now free to reuse
    float bv[4];
#pragma unroll
    for (int n = 0; n < 4; ++n) bv[n] = bias[ccol0 + (n << 4)];
    unsigned short* C = (unsigned short*)Cout;
    unsigned char* myl = lds + w * 9216;   // 32 rows x 288B (72 words, 2-way banks)
    const int lw = l & 15;
    const int lg = l >> 4;
    for (int mp = 0; mp < 4; ++mp) {       // 2 m-frags (32 rows) per pass
#pragma unroll
      for (int m2 = 0; m2 < 2; ++m2) {
        const int m = mp * 2 + m2;
#pragma unroll
        for (int n = 0; n < 4; ++n) {
#pragma unroll
          for (int r = 0; r < 4; ++r) {
            const float v = fmaxf(acc[m][n][r] + bv[n], 0.0f);
            const int row = m2 * 16 + lg * 4 + r;          // 0..31
            *(float*)(myl + row * 288 + ((n * 16 + lw) << 2)) = v;
          }
        }
      }
      LGKMCNT0;                     // cross-lane LDS visibility
      __builtin_amdgcn_sched_barrier(0);
#pragma unroll
      for (int k = 0; k < 8; ++k) {
        const int row = k * 4 + lg;                        // 0..31
        const float4 t = *(const float4*)(myl + row * 288 + (lw << 4));
        ushort4 o;
        o.x = f32_to_bf16_rn(t.x);
        o.y = f32_to_bf16_rn(t.y);
        o.z = f32_to_bf16_rn(t.z);
        o.w = f32_to_bf16_rn(t.w);
        const int grow = (bmi << 8) + (wr << 7) + (mp << 5) + row;
        const int gcol = (bni << 8) + (wc << 6) + (lw << 2);
        *(ushort4*)(C + (size_t)grow * N + gcol) = o;
      }
      LGKMCNT0;                     // reads done before next pass overwrites
      __builtin_amdgcn_sched_barrier(0);
    }
  } else {
    // f32 stores: 16 lanes x 4B = full 64B lines already; direct.
    float* C = (float*)Cout;
#pragma unroll
    for (int n = 0; n < 4; ++n) {
      const int col = ccol0 + (n << 4);
      const float bv = bias[col];
#pragma unroll
      for (int m = 0; m < 8; ++m) {
#pragma unroll
        for (int r = 0; r < 4; ++r) {
          C[(size_t)(crow0 + (m << 4) + r) * N + col] = acc[m][n][r] + bv;
        }
      }
    }
  }
}

extern "C" void kernel_launch(void* const* d_in, const int* in_sizes, int n_in,
                              void* d_out, int out_size, void* d_ws, size_t ws_size,
                              hipStream_t stream) {
  const float* x  = (const float*)d_in[0];  // [16384,1024]
  const float* W1 = (const float*)d_in[1];  // [4096,1024]
  const float* b1 = (const float*)d_in[2];  // [4096]
  const float* W2 = (const float*)d_in[3];  // [1024,4096]
  const float* b2 = (const float*)d_in[4];  // [1024]
  float* out = (float*)d_out;               // [16384,1024]

  const int M = 16384, H = 1024, F = 4096;

  unsigned short* xb  = (unsigned short*)d_ws;          // M*H bf16 (32 MiB)
  unsigned short* w1b = xb + (size_t)M * H;             // F*H bf16 (8 MiB)
  unsigned short* w2b = w1b + (size_t)F * H;            // H*F bf16 (8 MiB)
  unsigned short* act = w2b + (size_t)H * F;            // M*F bf16 (128 MiB)

  cvt_all<<<2048, 256, 0, stream>>>(x, W1, W2, xb, w1b, w2b,
                                    (M * H) / 4, (F * H) / 4);

  // GEMM1: act = relu(x @ W1^T + b1), bf16 out. M=16384, N=4096, K=1024.
  gemm8<1, 16><<<dim3((M / 256) * (F / 256)), 512, 0, stream>>>(xb, w1b, b1, act, H);
  // GEMM2: out = act @ W2^T + b2, f32 out. M=16384, N=1024, K=4096.
  gemm8<0, 4><<<dim3((M / 256) * (H / 256)), 512, 0, stream>>>(act, w2b, b2, out, F);
}